// Round 1
// baseline (275.507 us; speedup 1.0000x reference)
//
#include <hip/hip_runtime.h>
#include <math.h>

#define NBLOCKS 1024
#define BS 256

// Partials layout in d_ws (doubles):
// [0*NBLOCKS .. 1*NBLOCKS) : sum_all
// [1*NBLOCKS .. 2*NBLOCKS) : sum0 (y==0)
// [2*NBLOCKS .. 3*NBLOCKS) : cnt0 (as double, exact)
// [3*NBLOCKS .. 4*NBLOCKS) : min
// [4*NBLOCKS .. 5*NBLOCKS) : max

__global__ __launch_bounds__(BS) void risk_pass1(const float* __restrict__ x,
                                                 const int* __restrict__ y,
                                                 double* __restrict__ ws,
                                                 int n4) {
    const float4* __restrict__ x4 = (const float4*)x;
    const int4*   __restrict__ y4 = (const int4*)y;

    double sum = 0.0, sum0 = 0.0;
    long long cnt0 = 0;
    float mn =  INFINITY;
    float mx = -INFINITY;

    int stride = gridDim.x * blockDim.x;
    for (int i = blockIdx.x * blockDim.x + threadIdx.x; i < n4; i += stride) {
        float4 xv = x4[i];
        int4   yv = y4[i];
        sum += (double)xv.x + (double)xv.y + (double)xv.z + (double)xv.w;
        // predicated accumulate for label-0 group
        sum0 += (yv.x == 0) ? (double)xv.x : 0.0;
        sum0 += (yv.y == 0) ? (double)xv.y : 0.0;
        sum0 += (yv.z == 0) ? (double)xv.z : 0.0;
        sum0 += (yv.w == 0) ? (double)xv.w : 0.0;
        cnt0 += (yv.x == 0) + (yv.y == 0) + (yv.z == 0) + (yv.w == 0);
        mn = fminf(mn, fminf(fminf(xv.x, xv.y), fminf(xv.z, xv.w)));
        mx = fmaxf(mx, fmaxf(fmaxf(xv.x, xv.y), fmaxf(xv.z, xv.w)));
    }

    // wave (64-lane) reduction
    for (int off = 32; off > 0; off >>= 1) {
        sum  += __shfl_down(sum,  off);
        sum0 += __shfl_down(sum0, off);
        cnt0 += __shfl_down(cnt0, off);
        mn = fminf(mn, __shfl_down(mn, off));
        mx = fmaxf(mx, __shfl_down(mx, off));
    }

    __shared__ double s_sum[BS / 64], s_sum0[BS / 64];
    __shared__ long long s_cnt[BS / 64];
    __shared__ float s_mn[BS / 64], s_mx[BS / 64];

    int lane = threadIdx.x & 63;
    int wave = threadIdx.x >> 6;
    if (lane == 0) {
        s_sum[wave] = sum; s_sum0[wave] = sum0; s_cnt[wave] = cnt0;
        s_mn[wave] = mn; s_mx[wave] = mx;
    }
    __syncthreads();

    if (threadIdx.x == 0) {
        double bsum = s_sum[0], bsum0 = s_sum0[0];
        long long bcnt = s_cnt[0];
        float bmn = s_mn[0], bmx = s_mx[0];
        #pragma unroll
        for (int w = 1; w < BS / 64; ++w) {
            bsum += s_sum[w]; bsum0 += s_sum0[w]; bcnt += s_cnt[w];
            bmn = fminf(bmn, s_mn[w]); bmx = fmaxf(bmx, s_mx[w]);
        }
        ws[0 * NBLOCKS + blockIdx.x] = bsum;
        ws[1 * NBLOCKS + blockIdx.x] = bsum0;
        ws[2 * NBLOCKS + blockIdx.x] = (double)bcnt;
        ws[3 * NBLOCKS + blockIdx.x] = (double)bmn;
        ws[4 * NBLOCKS + blockIdx.x] = (double)bmx;
    }
}

__global__ __launch_bounds__(BS) void risk_pass2(const double* __restrict__ ws,
                                                 float* __restrict__ out,
                                                 long long n_total) {
    double sum = 0.0, sum0 = 0.0, cnt0 = 0.0;
    double mn =  INFINITY;
    double mx = -INFINITY;

    for (int i = threadIdx.x; i < NBLOCKS; i += BS) {
        sum  += ws[0 * NBLOCKS + i];
        sum0 += ws[1 * NBLOCKS + i];
        cnt0 += ws[2 * NBLOCKS + i];
        mn = fmin(mn, ws[3 * NBLOCKS + i]);
        mx = fmax(mx, ws[4 * NBLOCKS + i]);
    }

    for (int off = 32; off > 0; off >>= 1) {
        sum  += __shfl_down(sum,  off);
        sum0 += __shfl_down(sum0, off);
        cnt0 += __shfl_down(cnt0, off);
        mn = fmin(mn, __shfl_down(mn, off));
        mx = fmax(mx, __shfl_down(mx, off));
    }

    __shared__ double s_sum[BS / 64], s_sum0[BS / 64], s_cnt[BS / 64];
    __shared__ double s_mn[BS / 64], s_mx[BS / 64];
    int lane = threadIdx.x & 63;
    int wave = threadIdx.x >> 6;
    if (lane == 0) {
        s_sum[wave] = sum; s_sum0[wave] = sum0; s_cnt[wave] = cnt0;
        s_mn[wave] = mn; s_mx[wave] = mx;
    }
    __syncthreads();

    if (threadIdx.x == 0) {
        double tsum = s_sum[0], tsum0 = s_sum0[0], tcnt0 = s_cnt[0];
        double tmn = s_mn[0], tmx = s_mx[0];
        #pragma unroll
        for (int w = 1; w < BS / 64; ++w) {
            tsum += s_sum[w]; tsum0 += s_sum0[w]; tcnt0 += s_cnt[w];
            tmn = fmin(tmn, s_mn[w]); tmx = fmax(tmx, s_mx[w]);
        }
        double range = tmx - tmn;
        double n1 = (double)n_total - tcnt0;
        double sum1 = tsum - tsum0;
        // mean of normalized values = (raw mean - xmin) / range
        double m0 = (tsum0 / tcnt0 - tmn) / range;
        double m1 = (sum1  / n1    - tmn) / range;
        double l = fmin(m0, m1) - fmax(m0, m1);  // = -|m0 - m1|
        out[0] = (float)l;
    }
}

extern "C" void kernel_launch(void* const* d_in, const int* in_sizes, int n_in,
                              void* d_out, int out_size, void* d_ws, size_t ws_size,
                              hipStream_t stream) {
    const float* x = (const float*)d_in[0];
    const int*   y = (const int*)d_in[1];
    float* out = (float*)d_out;
    double* ws = (double*)d_ws;
    long long n = (long long)in_sizes[0];
    int n4 = (int)(n / 4);  // N = 2^25, divisible by 4

    risk_pass1<<<NBLOCKS, BS, 0, stream>>>(x, y, ws, n4);
    risk_pass2<<<1, BS, 0, stream>>>(ws, out, n);
}